// Round 9
// baseline (261.222 us; speedup 1.0000x reference)
//
#include <hip/hip_runtime.h>
#include <hip/hip_bf16.h>
#include <hip/hip_fp16.h>
#include <math.h>

#define NN 50000
#define EE 800000

__device__ __forceinline__ float lrelu(float v){ return v > 0.f ? v : 0.2f * v; }
__device__ __forceinline__ float sel4(float4 v, int h){
  return h == 0 ? v.x : h == 1 ? v.y : h == 2 ? v.z : v.w;
}
__device__ __forceinline__ ushort f2bf(float x){
  union { __hip_bfloat16 b; ushort u; } cv; cv.b = __float2bfloat16(x); return cv.u;
}
__device__ __forceinline__ float bf2f(ushort u){
  union { uint u; float f; } cv; cv.u = (uint)u << 16; return cv.f;
}
__device__ __forceinline__ ushort f2h(float x){
  union { __half h; ushort u; } cv; cv.h = __float2half(x); return cv.u;
}
__device__ __forceinline__ float h2f(ushort u){
  union { ushort u; __half h; } cv; cv.u = u; return __half2float(cv.h);
}

typedef __attribute__((ext_vector_type(8))) short bf16x8;
typedef __attribute__((ext_vector_type(4))) float f32x4;

// async global->LDS, 16B per lane
__device__ __forceinline__ void gload16(const ushort* g, ushort* l){
  const auto* gp = reinterpret_cast<const __attribute__((address_space(1))) ushort*>((size_t)g);
  auto* lp = reinterpret_cast<__attribute__((address_space(3))) ushort*>((size_t)l);
  __builtin_amdgcn_global_load_lds(gp, lp, 16, 0, 0);
}

// ---------------- CSR build ----------------
__global__ void k_hist(const int* __restrict__ dst, int* __restrict__ cnt, int E){
  int i = blockIdx.x * blockDim.x + threadIdx.x;
  if (i < E) atomicAdd(&cnt[dst[i]], 1);
}

__global__ __launch_bounds__(1024) void k_scan_bsum(const int* __restrict__ cnt, int* __restrict__ bsum, int n){
  __shared__ int ws[16];
  int t = threadIdx.x, i = blockIdx.x*1024 + t;
  int v = (i < n) ? cnt[i] : 0;
  #pragma unroll
  for (int off = 32; off; off >>= 1) v += __shfl_down(v, off);
  if ((t & 63) == 0) ws[t >> 6] = v;
  __syncthreads();
  if (t < 64){
    int x = (t < 16) ? ws[t] : 0;
    #pragma unroll
    for (int off = 32; off; off >>= 1) x += __shfl_down(x, off);
    if (t == 0) bsum[blockIdx.x] = x;
  }
}

__global__ void k_scan_boff(const int* __restrict__ bsum, int* __restrict__ boff,
                            int nb, int* __restrict__ rowptr, int n){
  int t = threadIdx.x;
  int v = (t < nb) ? bsum[t] : 0;
  int x = v;
  #pragma unroll
  for (int off = 1; off < 64; off <<= 1){ int y = __shfl_up(x, off); if (t >= off) x += y; }
  if (t < nb) boff[t] = x - v;
  if (t == 63) rowptr[n] = x;
}

__global__ __launch_bounds__(1024) void k_scan_write(const int* __restrict__ cnt, const int* __restrict__ boff,
                                                     int* __restrict__ rowptr, int* __restrict__ cursor, int n){
  __shared__ int ws[16];
  int t = threadIdx.x, w = t >> 6, lane = t & 63, i = blockIdx.x*1024 + t;
  int v = (i < n) ? cnt[i] : 0;
  int x = v;
  #pragma unroll
  for (int off = 1; off < 64; off <<= 1){ int y = __shfl_up(x, off); if (lane >= off) x += y; }
  if (lane == 63) ws[w] = x;
  __syncthreads();
  if (t < 16){
    int y = ws[t];
    #pragma unroll
    for (int off = 1; off < 16; off <<= 1){ int z = __shfl_up(y, off); if (t >= off) y += z; }
    ws[t] = y;
  }
  __syncthreads();
  if (i < n){
    int ex = boff[blockIdx.x] + ((w > 0) ? ws[w-1] : 0) + x - v;
    rowptr[i] = ex;
    cursor[i] = ex;
  }
}

__global__ void k_scatter(const int* __restrict__ src, const int* __restrict__ dst,
                          int* __restrict__ cursor, int* __restrict__ csr_src, int E){
  int i = blockIdx.x * blockDim.x + threadIdx.x;
  if (i < E){ int p = atomicAdd(&cursor[dst[i]], 1); csr_src[p] = src[i]; }
}

// ---------------- merged prep: A->bf16, W1/W2 -> transposed split-bf16 ----------------
__global__ void k_prep(const float* __restrict__ A, ushort* __restrict__ Ab,
                       const float* __restrict__ W1, ushort* __restrict__ Bth1, ushort* __restrict__ Btl1,
                       const float* __restrict__ W2, ushort* __restrict__ Bth2, ushort* __restrict__ Btl2){
  int b = blockIdx.x, t = threadIdx.x;
  if (b < 12500){
    int i = b*256 + t;
    float4 v = ((const float4*)A)[i];
    ((ushort4*)Ab)[i] = make_ushort4(f2bf(v.x), f2bf(v.y), f2bf(v.z), f2bf(v.w));
  } else if (b < 12756){
    int k = b - 12500;
    float x = W1[(size_t)k*256 + t];
    ushort h = f2bf(x);
    Bth1[(size_t)t*256 + k] = h;
    Btl1[(size_t)t*256 + k] = f2bf(x - bf2f(h));
  } else {
    int k = b - 12756;
    if (t < 128){
      float x = W2[(size_t)k*128 + t];
      ushort h = f2bf(x);
      Bth2[(size_t)t*256 + k] = h;
      Btl2[(size_t)t*256 + k] = f2bf(x - bf2f(h));
    }
  }
}

// ---------------- bf16-A x split-bf16-B MFMA GEMM + fused el/er epilogue ----------------
template<int MODE>
__global__ __launch_bounds__(512, 4) void k_mgemm(
    const ushort* __restrict__ Ab,
    const ushort* __restrict__ Bth, const ushort* __restrict__ Btl,
    void* __restrict__ Cout, const float* __restrict__ avl, const float* __restrict__ avr,
    float* __restrict__ el, float* __restrict__ er, int M, int K, int N)
{
  __shared__ __align__(16) ushort sA[2][128*32];
  __shared__ __align__(16) ushort sBh[2][128*32];
  __shared__ __align__(16) ushort sBl[2][128*32];
  __shared__ float sEL[2][128], sER[2][128];
  int tid = threadIdx.x;
  int w = tid >> 6, lane = tid & 63;
  int bm = blockIdx.y*128, bn = blockIdx.x*128;
  int wm = (w & 3)*32, wn = (w >> 2)*64;
  int fr = lane & 15, fg = lane >> 4;

  int srow = 16*w + (lane >> 2);
  int skoff = (lane & 3)*8;
  int arow = bm + srow; if (arow > M-1) arow = M-1;
  const ushort* gA  = Ab  + (size_t)arow*K + skoff;
  const ushort* gBh = Bth + (size_t)(bn + srow)*K + skoff;
  const ushort* gBl = Btl + (size_t)(bn + srow)*K + skoff;
  int lslice = 16*w*32;

  const int nk = K >> 5;
  gload16(gA,  &sA[0][lslice]);
  gload16(gBh, &sBh[0][lslice]);
  gload16(gBl, &sBl[0][lslice]);
  __syncthreads();

  f32x4 acc[2][4] = {};
  for (int kt = 0; kt < nk; ++kt){
    int buf = kt & 1;
    if (kt + 1 < nk){
      int k1 = (kt + 1) << 5;
      gload16(gA + k1,  &sA[buf^1][lslice]);
      gload16(gBh + k1, &sBh[buf^1][lslice]);
      gload16(gBl + k1, &sBl[buf^1][lslice]);
    }
    bf16x8 ah[2], bh[4], bl[4];
    #pragma unroll
    for (int ti = 0; ti < 2; ++ti)
      ah[ti] = *(const bf16x8*)&sA[buf][(wm + ti*16 + fr)*32 + fg*8];
    #pragma unroll
    for (int tj = 0; tj < 4; ++tj){
      int bi = (wn + tj*16 + fr)*32 + fg*8;
      bh[tj] = *(const bf16x8*)&sBh[buf][bi];
      bl[tj] = *(const bf16x8*)&sBl[buf][bi];
    }
    #pragma unroll
    for (int ti = 0; ti < 2; ++ti)
      #pragma unroll
      for (int tj = 0; tj < 4; ++tj){
        acc[ti][tj] = __builtin_amdgcn_mfma_f32_16x16x32_bf16(ah[ti], bh[tj], acc[ti][tj], 0,0,0);
        acc[ti][tj] = __builtin_amdgcn_mfma_f32_16x16x32_bf16(ah[ti], bl[tj], acc[ti][tj], 0,0,0);
      }
    __syncthreads();
  }

  int colhead = bn + wn;
  float wl[4], wr[4];
  #pragma unroll
  for (int tj = 0; tj < 4; ++tj){
    int c = colhead + tj*16 + fr;
    wl[tj] = avl[c]; wr[tj] = avr[c];
  }
  #pragma unroll
  for (int ti = 0; ti < 2; ++ti)
    #pragma unroll
    for (int i = 0; i < 4; ++i){
      int row = bm + wm + ti*16 + fg*4 + i;
      float pl = 0.f, pr = 0.f;
      #pragma unroll
      for (int tj = 0; tj < 4; ++tj){
        float v = acc[ti][tj][i];
        pl = fmaf(v, wl[tj], pl);
        pr = fmaf(v, wr[tj], pr);
        if (row < M){
          int col = colhead + tj*16 + fr;
          if (MODE == 1) ((ushort*)Cout)[(size_t)row*256 + col] = f2bf(v);
          else           ((ushort*)Cout)[(size_t)row*128 + col] = f2h(v);
        }
      }
      #pragma unroll
      for (int mk = 1; mk < 16; mk <<= 1){
        pl += __shfl_xor(pl, mk);
        pr += __shfl_xor(pr, mk);
      }
      if (fr == 0){
        if (MODE == 1){
          if (row < M){ el[row*4 + (colhead >> 6)] = pl; er[row*4 + (colhead >> 6)] = pr; }
        } else {
          int lr = wm + ti*16 + fg*4 + i;
          sEL[w >> 2][lr] = pl; sER[w >> 2][lr] = pr;
        }
      }
    }
  if (MODE == 2){
    __syncthreads();
    if (tid < 128){
      int row = bm + tid;
      if (row < M){
        el[row] = sEL[0][tid] + sEL[1][tid];
        er[row] = sER[0][tid] + sER[1][tid];
      }
    }
  }
}

// ---------------- fused softmax+aggregate, layer 1 (bf16 gather, no-max softmax) ----------------
__global__ __launch_bounds__(256) void k_fused1(
    const int* __restrict__ rowptr, const int* __restrict__ csr_src,
    const float* __restrict__ el, const float* __restrict__ er,
    const ushort* __restrict__ featb, ushort* __restrict__ h1b)
{
  __shared__ __align__(16) float p_sh[4][64*4];
  __shared__ int si_sh[4][64];
  int w = threadIdx.x >> 6, lane = threadIdx.x & 63;
  int n = blockIdx.x*4 + w;
  if (n >= NN) return;
  int b = rowptr[n], deg = rowptr[n+1] - b;
  int h = lane >> 4;
  float4 er4 = *(const float4*)&er[n*4];
  float4 s4 = make_float4(0,0,0,0);     // per-lane partial denominator
  float4 acc = make_float4(0,0,0,0);

  for (int c0 = 0; c0 < deg; c0 += 64){
    int C = min(64, deg - c0);
    int si = 0;
    float4 p4 = make_float4(0,0,0,0);
    if (lane < C){
      si = csr_src[b + c0 + lane];
      float4 l4 = *(const float4*)&el[si*4];
      p4.x = __expf(lrelu(l4.x + er4.x));
      p4.y = __expf(lrelu(l4.y + er4.y));
      p4.z = __expf(lrelu(l4.z + er4.z));
      p4.w = __expf(lrelu(l4.w + er4.w));
    }
    s4.x += p4.x; s4.y += p4.y; s4.z += p4.z; s4.w += p4.w;
    *(float4*)&p_sh[w][lane*4] = p4;
    si_sh[w][lane] = si;
    #pragma unroll 8
    for (int j = 0; j < C; ++j){
      float a = p_sh[w][j*4 + h];
      int sj = si_sh[w][j];
      ushort4 u = *(const ushort4*)&featb[(size_t)sj*256 + lane*4];
      acc.x = fmaf(a, bf2f(u.x), acc.x); acc.y = fmaf(a, bf2f(u.y), acc.y);
      acc.z = fmaf(a, bf2f(u.z), acc.z); acc.w = fmaf(a, bf2f(u.w), acc.w);
    }
  }
  // single wave reduce of the denominator
  #pragma unroll
  for (int off = 32; off; off >>= 1){
    s4.x += __shfl_xor(s4.x, off); s4.y += __shfl_xor(s4.y, off);
    s4.z += __shfl_xor(s4.z, off); s4.w += __shfl_xor(s4.w, off);
  }
  float4 o = make_float4(0,0,0,0);
  if (deg > 0){
    float rs = 1.0f / sel4(s4, h);
    o.x = acc.x * rs; o.y = acc.y * rs; o.z = acc.z * rs; o.w = acc.w * rs;
    o.x = o.x > 0.f ? o.x : expm1f(o.x);
    o.y = o.y > 0.f ? o.y : expm1f(o.y);
    o.z = o.z > 0.f ? o.z : expm1f(o.z);
    o.w = o.w > 0.f ? o.w : expm1f(o.w);
  }
  ushort4 ob = make_ushort4(f2bf(o.x), f2bf(o.y), f2bf(o.z), f2bf(o.w));
  *(ushort4*)&h1b[(size_t)n*256 + lane*4] = ob;
}

// ---------------- fused softmax+aggregate, layer 2 (f16 gather, no-max softmax) ----------------
__global__ __launch_bounds__(256) void k_fused2(
    const int* __restrict__ rowptr, const int* __restrict__ csr_src,
    const float* __restrict__ el, const float* __restrict__ er,
    const ushort* __restrict__ featH, float* __restrict__ out)
{
  __shared__ float p_sh[4][64];
  __shared__ int si_sh[4][64];
  int w = threadIdx.x >> 6, lane = threadIdx.x & 63;
  int n = blockIdx.x*4 + w;
  if (n >= NN) return;
  int b = rowptr[n], deg = rowptr[n+1] - b;
  float er_n = er[n];
  float s = 0.f;
  float4 acc = make_float4(0,0,0,0);
  int half = lane >> 5, l32 = lane & 31;

  for (int c0 = 0; c0 < deg; c0 += 64){
    int C = min(64, deg - c0);
    int si = 0;
    float p = 0.f;
    if (lane < C){
      si = csr_src[b + c0 + lane];
      p = __expf(lrelu(el[si] + er_n));
    }
    s += p;
    p_sh[w][lane] = p;
    si_sh[w][lane] = si;
    int iters = (C + 1) >> 1;
    #pragma unroll 8
    for (int it = 0; it < iters; ++it){
      int e0 = 2*it + half;
      float a = p_sh[w][e0];
      int sj = si_sh[w][e0];
      ushort4 u = *(const ushort4*)&featH[(size_t)sj*128 + l32*4];
      acc.x = fmaf(a, h2f(u.x), acc.x); acc.y = fmaf(a, h2f(u.y), acc.y);
      acc.z = fmaf(a, h2f(u.z), acc.z); acc.w = fmaf(a, h2f(u.w), acc.w);
    }
  }
  #pragma unroll
  for (int off = 32; off; off >>= 1) s += __shfl_xor(s, off);
  acc.x += __shfl_xor(acc.x, 32); acc.y += __shfl_xor(acc.y, 32);
  acc.z += __shfl_xor(acc.z, 32); acc.w += __shfl_xor(acc.w, 32);
  if (lane < 32){
    float4 o = make_float4(0,0,0,0);
    if (deg > 0){
      float rs = 1.0f / s;
      o.x = acc.x*rs; o.y = acc.y*rs; o.z = acc.z*rs; o.w = acc.w*rs;
    }
    *(float4*)&out[(size_t)n*128 + l32*4] = o;
  }
}

// ---------------- host launch ----------------
static inline size_t align256(size_t x){ return (x + 255) & ~(size_t)255; }

extern "C" void kernel_launch(void* const* d_in, const int* in_sizes, int n_in,
                              void* d_out, int out_size, void* d_ws, size_t ws_size,
                              hipStream_t stream){
  const float* h_in = (const float*)d_in[0];
  const int*   src  = (const int*)d_in[1];
  const int*   dst  = (const int*)d_in[2];
  const float* W1   = (const float*)d_in[3];
  const float* al1  = (const float*)d_in[4];
  const float* ar1  = (const float*)d_in[5];
  const float* W2   = (const float*)d_in[6];
  const float* al2  = (const float*)d_in[7];
  const float* ar2  = (const float*)d_in[8];
  float* out = (float*)d_out;

  char* ws = (char*)d_ws;
  size_t off = 0;
  ushort* Ab     = (ushort*)(ws + off); off = align256(off + (size_t)NN*256*2);  // reused as h1b
  ushort* featb  = (ushort*)(ws + off); off = align256(off + (size_t)NN*256*2);
  ushort* feat2  = (ushort*)(ws + off); off = align256(off + (size_t)NN*128*2);  // f16
  float* el1     = (float*)(ws + off);  off = align256(off + (size_t)NN*4*4);
  float* er1     = (float*)(ws + off);  off = align256(off + (size_t)NN*4*4);
  int* rowptr    = (int*)(ws + off);    off = align256(off + (size_t)(NN+1)*4);
  int* cnt       = (int*)(ws + off);    off = align256(off + (size_t)NN*4);
  int* cursor    = (int*)(ws + off);    off = align256(off + (size_t)NN*4);
  int* csr_src   = (int*)(ws + off);    off = align256(off + (size_t)EE*4);
  ushort* Bth1   = (ushort*)(ws + off); off = align256(off + (size_t)256*256*2);
  ushort* Btl1   = (ushort*)(ws + off); off = align256(off + (size_t)256*256*2);
  ushort* Bth2   = (ushort*)(ws + off); off = align256(off + (size_t)128*256*2);
  ushort* Btl2   = (ushort*)(ws + off); off = align256(off + (size_t)128*256*2);
  int* bsum      = (int*)(ws + off);    off = align256(off + (size_t)64*4);
  int* boff      = (int*)(ws + off);    off = align256(off + (size_t)64*4);
  if (off > ws_size) return;  // fail loudly: output stays poisoned

  ushort* h1b = Ab;
  float* el2 = el1;
  float* er2 = er1;

  const int EB = (EE + 255)/256;
  const int FB = (NN + 3)/4;
  const int NB = (NN + 1023)/1024;
  const int MT = (NN + 127)/128;

  // CSR build
  hipMemsetAsync(cnt, 0, (size_t)NN*4, stream);
  k_hist<<<EB, 256, 0, stream>>>(dst, cnt, EE);
  k_scan_bsum<<<NB, 1024, 0, stream>>>(cnt, bsum, NN);
  k_scan_boff<<<1, 64, 0, stream>>>(bsum, boff, NB, rowptr, NN);
  k_scan_write<<<NB, 1024, 0, stream>>>(cnt, boff, rowptr, cursor, NN);
  k_scatter<<<EB, 256, 0, stream>>>(src, dst, cursor, csr_src, EE);

  // merged prep
  k_prep<<<13012, 256, 0, stream>>>(h_in, Ab, W1, Bth1, Btl1, W2, Bth2, Btl2);

  // ----- layer 1 -----
  k_mgemm<1><<<dim3(2, MT), 512, 0, stream>>>(Ab, Bth1, Btl1, featb, al1, ar1, el1, er1, NN, 256, 256);
  k_fused1<<<FB, 256, 0, stream>>>(rowptr, csr_src, el1, er1, featb, h1b);

  // ----- layer 2 -----
  k_mgemm<2><<<dim3(1, MT), 512, 0, stream>>>(h1b, Bth2, Btl2, feat2, al2, ar2, el2, er2, NN, 256, 128);
  k_fused2<<<FB, 256, 0, stream>>>(rowptr, csr_src, el2, er2, feat2, out);
}

// Round 10
// 254.526 us; speedup vs baseline: 1.0263x; 1.0263x over previous
//
#include <hip/hip_runtime.h>
#include <hip/hip_bf16.h>
#include <hip/hip_fp16.h>
#include <math.h>

#define NN 50000
#define EE 800000

__device__ __forceinline__ float lrelu(float v){ return v > 0.f ? v : 0.2f * v; }
__device__ __forceinline__ float sel4(float4 v, int h){
  return h == 0 ? v.x : h == 1 ? v.y : h == 2 ? v.z : v.w;
}
__device__ __forceinline__ ushort f2bf(float x){
  union { __hip_bfloat16 b; ushort u; } cv; cv.b = __float2bfloat16(x); return cv.u;
}
__device__ __forceinline__ float bf2f(ushort u){
  union { uint u; float f; } cv; cv.u = (uint)u << 16; return cv.f;
}
__device__ __forceinline__ ushort f2h(float x){
  union { __half h; ushort u; } cv; cv.h = __float2half(x); return cv.u;
}
// packed unpack helpers
__device__ __forceinline__ float bflo(uint u){ union{uint u; float f;} c; c.u = u << 16; return c.f; }
__device__ __forceinline__ float bfhi(uint u){ union{uint u; float f;} c; c.u = u & 0xffff0000u; return c.f; }
__device__ __forceinline__ float hlo(uint u){
  union{ ushort us; __half h; } c; c.us = (ushort)(u & 0xffffu); return __half2float(c.h);
}
__device__ __forceinline__ float hhi(uint u){
  union{ ushort us; __half h; } c; c.us = (ushort)(u >> 16); return __half2float(c.h);
}

typedef __attribute__((ext_vector_type(8))) short bf16x8;
typedef __attribute__((ext_vector_type(4))) float f32x4;

// async global->LDS, 16B per lane
__device__ __forceinline__ void gload16(const ushort* g, ushort* l){
  const auto* gp = reinterpret_cast<const __attribute__((address_space(1))) ushort*>((size_t)g);
  auto* lp = reinterpret_cast<__attribute__((address_space(3))) ushort*>((size_t)l);
  __builtin_amdgcn_global_load_lds(gp, lp, 16, 0, 0);
}

// ---------------- CSR build ----------------
__global__ void k_hist(const int* __restrict__ dst, int* __restrict__ cnt, int E){
  int i = blockIdx.x * blockDim.x + threadIdx.x;
  if (i < E) atomicAdd(&cnt[dst[i]], 1);
}

__global__ __launch_bounds__(1024) void k_scan_bsum(const int* __restrict__ cnt, int* __restrict__ bsum, int n){
  __shared__ int ws[16];
  int t = threadIdx.x, i = blockIdx.x*1024 + t;
  int v = (i < n) ? cnt[i] : 0;
  #pragma unroll
  for (int off = 32; off; off >>= 1) v += __shfl_down(v, off);
  if ((t & 63) == 0) ws[t >> 6] = v;
  __syncthreads();
  if (t < 64){
    int x = (t < 16) ? ws[t] : 0;
    #pragma unroll
    for (int off = 32; off; off >>= 1) x += __shfl_down(x, off);
    if (t == 0) bsum[blockIdx.x] = x;
  }
}

__global__ void k_scan_boff(const int* __restrict__ bsum, int* __restrict__ boff,
                            int nb, int* __restrict__ rowptr, int n){
  int t = threadIdx.x;
  int v = (t < nb) ? bsum[t] : 0;
  int x = v;
  #pragma unroll
  for (int off = 1; off < 64; off <<= 1){ int y = __shfl_up(x, off); if (t >= off) x += y; }
  if (t < nb) boff[t] = x - v;
  if (t == 63) rowptr[n] = x;
}

__global__ __launch_bounds__(1024) void k_scan_write(const int* __restrict__ cnt, const int* __restrict__ boff,
                                                     int* __restrict__ rowptr, int* __restrict__ cursor, int n){
  __shared__ int ws[16];
  int t = threadIdx.x, w = t >> 6, lane = t & 63, i = blockIdx.x*1024 + t;
  int v = (i < n) ? cnt[i] : 0;
  int x = v;
  #pragma unroll
  for (int off = 1; off < 64; off <<= 1){ int y = __shfl_up(x, off); if (lane >= off) x += y; }
  if (lane == 63) ws[w] = x;
  __syncthreads();
  if (t < 16){
    int y = ws[t];
    #pragma unroll
    for (int off = 1; off < 16; off <<= 1){ int z = __shfl_up(y, off); if (t >= off) y += z; }
    ws[t] = y;
  }
  __syncthreads();
  if (i < n){
    int ex = boff[blockIdx.x] + ((w > 0) ? ws[w-1] : 0) + x - v;
    rowptr[i] = ex;
    cursor[i] = ex;
  }
}

__global__ void k_scatter(const int* __restrict__ src, const int* __restrict__ dst,
                          int* __restrict__ cursor, int* __restrict__ csr_src, int E){
  int i = blockIdx.x * blockDim.x + threadIdx.x;
  if (i < E){ int p = atomicAdd(&cursor[dst[i]], 1); csr_src[p] = src[i]; }
}

// ---------------- merged prep: A->bf16, W1/W2 -> transposed split-bf16 ----------------
__global__ void k_prep(const float* __restrict__ A, ushort* __restrict__ Ab,
                       const float* __restrict__ W1, ushort* __restrict__ Bth1, ushort* __restrict__ Btl1,
                       const float* __restrict__ W2, ushort* __restrict__ Bth2, ushort* __restrict__ Btl2){
  int b = blockIdx.x, t = threadIdx.x;
  if (b < 12500){
    int i = b*256 + t;
    float4 v = ((const float4*)A)[i];
    ((ushort4*)Ab)[i] = make_ushort4(f2bf(v.x), f2bf(v.y), f2bf(v.z), f2bf(v.w));
  } else if (b < 12756){
    int k = b - 12500;
    float x = W1[(size_t)k*256 + t];
    ushort h = f2bf(x);
    Bth1[(size_t)t*256 + k] = h;
    Btl1[(size_t)t*256 + k] = f2bf(x - bf2f(h));
  } else {
    int k = b - 12756;
    if (t < 128){
      float x = W2[(size_t)k*128 + t];
      ushort h = f2bf(x);
      Bth2[(size_t)t*256 + k] = h;
      Btl2[(size_t)t*256 + k] = f2bf(x - bf2f(h));
    }
  }
}

// ---------------- bf16-A x split-bf16-B MFMA GEMM + fused el/er epilogue ----------------
template<int MODE>
__global__ __launch_bounds__(512, 4) void k_mgemm(
    const ushort* __restrict__ Ab,
    const ushort* __restrict__ Bth, const ushort* __restrict__ Btl,
    void* __restrict__ Cout, const float* __restrict__ avl, const float* __restrict__ avr,
    float* __restrict__ el, float* __restrict__ er, int M, int K, int N)
{
  __shared__ __align__(16) ushort sA[2][128*32];
  __shared__ __align__(16) ushort sBh[2][128*32];
  __shared__ __align__(16) ushort sBl[2][128*32];
  __shared__ float sEL[2][128], sER[2][128];
  int tid = threadIdx.x;
  int w = tid >> 6, lane = tid & 63;
  int bm = blockIdx.y*128, bn = blockIdx.x*128;
  int wm = (w & 3)*32, wn = (w >> 2)*64;
  int fr = lane & 15, fg = lane >> 4;

  int srow = 16*w + (lane >> 2);
  int skoff = (lane & 3)*8;
  int arow = bm + srow; if (arow > M-1) arow = M-1;
  const ushort* gA  = Ab  + (size_t)arow*K + skoff;
  const ushort* gBh = Bth + (size_t)(bn + srow)*K + skoff;
  const ushort* gBl = Btl + (size_t)(bn + srow)*K + skoff;
  int lslice = 16*w*32;

  const int nk = K >> 5;
  gload16(gA,  &sA[0][lslice]);
  gload16(gBh, &sBh[0][lslice]);
  gload16(gBl, &sBl[0][lslice]);
  __syncthreads();

  f32x4 acc[2][4] = {};
  for (int kt = 0; kt < nk; ++kt){
    int buf = kt & 1;
    if (kt + 1 < nk){
      int k1 = (kt + 1) << 5;
      gload16(gA + k1,  &sA[buf^1][lslice]);
      gload16(gBh + k1, &sBh[buf^1][lslice]);
      gload16(gBl + k1, &sBl[buf^1][lslice]);
    }
    bf16x8 ah[2], bh[4], bl[4];
    #pragma unroll
    for (int ti = 0; ti < 2; ++ti)
      ah[ti] = *(const bf16x8*)&sA[buf][(wm + ti*16 + fr)*32 + fg*8];
    #pragma unroll
    for (int tj = 0; tj < 4; ++tj){
      int bi = (wn + tj*16 + fr)*32 + fg*8;
      bh[tj] = *(const bf16x8*)&sBh[buf][bi];
      bl[tj] = *(const bf16x8*)&sBl[buf][bi];
    }
    #pragma unroll
    for (int ti = 0; ti < 2; ++ti)
      #pragma unroll
      for (int tj = 0; tj < 4; ++tj){
        acc[ti][tj] = __builtin_amdgcn_mfma_f32_16x16x32_bf16(ah[ti], bh[tj], acc[ti][tj], 0,0,0);
        acc[ti][tj] = __builtin_amdgcn_mfma_f32_16x16x32_bf16(ah[ti], bl[tj], acc[ti][tj], 0,0,0);
      }
    __syncthreads();
  }

  int colhead = bn + wn;
  float wl[4], wr[4];
  #pragma unroll
  for (int tj = 0; tj < 4; ++tj){
    int c = colhead + tj*16 + fr;
    wl[tj] = avl[c]; wr[tj] = avr[c];
  }
  #pragma unroll
  for (int ti = 0; ti < 2; ++ti)
    #pragma unroll
    for (int i = 0; i < 4; ++i){
      int row = bm + wm + ti*16 + fg*4 + i;
      float pl = 0.f, pr = 0.f;
      #pragma unroll
      for (int tj = 0; tj < 4; ++tj){
        float v = acc[ti][tj][i];
        pl = fmaf(v, wl[tj], pl);
        pr = fmaf(v, wr[tj], pr);
        if (row < M){
          int col = colhead + tj*16 + fr;
          if (MODE == 1) ((ushort*)Cout)[(size_t)row*256 + col] = f2bf(v);
          else           ((ushort*)Cout)[(size_t)row*128 + col] = f2h(v);
        }
      }
      #pragma unroll
      for (int mk = 1; mk < 16; mk <<= 1){
        pl += __shfl_xor(pl, mk);
        pr += __shfl_xor(pr, mk);
      }
      if (fr == 0){
        if (MODE == 1){
          if (row < M){ el[row*4 + (colhead >> 6)] = pl; er[row*4 + (colhead >> 6)] = pr; }
        } else {
          int lr = wm + ti*16 + fg*4 + i;
          sEL[w >> 2][lr] = pl; sER[w >> 2][lr] = pr;
        }
      }
    }
  if (MODE == 2){
    __syncthreads();
    if (tid < 128){
      int row = bm + tid;
      if (row < M){
        el[row] = sEL[0][tid] + sEL[1][tid];
        er[row] = sER[0][tid] + sER[1][tid];
      }
    }
  }
}

// ---------------- fused softmax+aggregate, layer 1 ----------------
// One wave per node. Softmax stage: edge = lane (chunk of 64). Aggregate: each
// HALF-WAVE (32 lanes x 16B uint4) reads a full 512B bf16 row -> 2 edges per
// VMEM instruction, unroll 4 -> 8 rows in flight. Lane covers 8 cols.
__global__ __launch_bounds__(256) void k_fused1(
    const int* __restrict__ rowptr, const int* __restrict__ csr_src,
    const float* __restrict__ el, const float* __restrict__ er,
    const ushort* __restrict__ featb, ushort* __restrict__ h1b)
{
  __shared__ __align__(16) float p_sh[4][64*4];
  __shared__ int si_sh[4][64];
  int w = threadIdx.x >> 6, lane = threadIdx.x & 63;
  int n = blockIdx.x*4 + w;
  if (n >= NN) return;
  int b = rowptr[n], deg = rowptr[n+1] - b;
  int l32 = lane & 31, half = lane >> 5;
  int h = l32 >> 3;                        // head of this lane's 8-col slice
  float4 er4 = *(const float4*)&er[n*4];
  float4 s4 = make_float4(0,0,0,0);
  float acc[8] = {0.f,0.f,0.f,0.f,0.f,0.f,0.f,0.f};

  for (int c0 = 0; c0 < deg; c0 += 64){
    int C = min(64, deg - c0);
    int si = 0;
    float4 p4 = make_float4(0,0,0,0);
    if (lane < C){
      si = csr_src[b + c0 + lane];
      float4 l4 = *(const float4*)&el[si*4];
      p4.x = __expf(lrelu(l4.x + er4.x));
      p4.y = __expf(lrelu(l4.y + er4.y));
      p4.z = __expf(lrelu(l4.z + er4.z));
      p4.w = __expf(lrelu(l4.w + er4.w));
    }
    s4.x += p4.x; s4.y += p4.y; s4.z += p4.z; s4.w += p4.w;
    *(float4*)&p_sh[w][lane*4] = p4;       // unconditional: zero-pads beyond C
    si_sh[w][lane] = si;
    #pragma unroll 4
    for (int j = 0; j < C; j += 2){
      int e = j + half;                    // e <= 63 always; p_sh zero beyond C
      float a = p_sh[w][e*4 + h];
      int sj = si_sh[w][e];
      uint4 u = *(const uint4*)&featb[(size_t)sj*256 + l32*8];
      acc[0] = fmaf(a, bflo(u.x), acc[0]); acc[1] = fmaf(a, bfhi(u.x), acc[1]);
      acc[2] = fmaf(a, bflo(u.y), acc[2]); acc[3] = fmaf(a, bfhi(u.y), acc[3]);
      acc[4] = fmaf(a, bflo(u.z), acc[4]); acc[5] = fmaf(a, bfhi(u.z), acc[5]);
      acc[6] = fmaf(a, bflo(u.w), acc[6]); acc[7] = fmaf(a, bfhi(u.w), acc[7]);
    }
  }
  // combine half-wave partials
  #pragma unroll
  for (int k = 0; k < 8; ++k) acc[k] += __shfl_xor(acc[k], 32);
  // denominator reduce
  #pragma unroll
  for (int off = 32; off; off >>= 1){
    s4.x += __shfl_xor(s4.x, off); s4.y += __shfl_xor(s4.y, off);
    s4.z += __shfl_xor(s4.z, off); s4.w += __shfl_xor(s4.w, off);
  }
  if (lane < 32){
    float rs = (deg > 0) ? 1.0f / sel4(s4, h) : 0.f;
    ushort ob[8];
    #pragma unroll
    for (int k = 0; k < 8; ++k){
      float v = acc[k] * rs;
      v = (v > 0.f) ? v : expm1f(v);
      ob[k] = f2bf(v);
    }
    uint4 pk;
    pk.x = (uint)ob[0] | ((uint)ob[1] << 16);
    pk.y = (uint)ob[2] | ((uint)ob[3] << 16);
    pk.z = (uint)ob[4] | ((uint)ob[5] << 16);
    pk.w = (uint)ob[6] | ((uint)ob[7] << 16);
    *(uint4*)&h1b[(size_t)n*256 + l32*8] = pk;
  }
}

// ---------------- fused softmax+aggregate, layer 2 ----------------
// One wave per node. Aggregate: each 16-LANE GROUP (16 x 16B) reads a full
// 256B f16 row -> 4 edges per VMEM instruction, unroll 4 -> 16 rows in flight.
__global__ __launch_bounds__(256) void k_fused2(
    const int* __restrict__ rowptr, const int* __restrict__ csr_src,
    const float* __restrict__ el, const float* __restrict__ er,
    const ushort* __restrict__ featH, float* __restrict__ out)
{
  __shared__ float p_sh[4][64];
  __shared__ int si_sh[4][64];
  int w = threadIdx.x >> 6, lane = threadIdx.x & 63;
  int n = blockIdx.x*4 + w;
  if (n >= NN) return;
  int b = rowptr[n], deg = rowptr[n+1] - b;
  int l16 = lane & 15, grp = lane >> 4;
  float er_n = er[n];
  float s = 0.f;
  float acc[8] = {0.f,0.f,0.f,0.f,0.f,0.f,0.f,0.f};

  for (int c0 = 0; c0 < deg; c0 += 64){
    int C = min(64, deg - c0);
    int si = 0;
    float p = 0.f;
    if (lane < C){
      si = csr_src[b + c0 + lane];
      p = __expf(lrelu(el[si] + er_n));
    }
    s += p;
    p_sh[w][lane] = p;
    si_sh[w][lane] = si;
    #pragma unroll 4
    for (int j = 0; j < C; j += 4){
      int e = j + grp;                     // e <= 63 always; p zero beyond C
      float a = p_sh[w][e];
      int sj = si_sh[w][e];
      uint4 u = *(const uint4*)&featH[(size_t)sj*128 + l16*8];
      acc[0] = fmaf(a, hlo(u.x), acc[0]); acc[1] = fmaf(a, hhi(u.x), acc[1]);
      acc[2] = fmaf(a, hlo(u.y), acc[2]); acc[3] = fmaf(a, hhi(u.y), acc[3]);
      acc[4] = fmaf(a, hlo(u.z), acc[4]); acc[5] = fmaf(a, hhi(u.z), acc[5]);
      acc[6] = fmaf(a, hlo(u.w), acc[6]); acc[7] = fmaf(a, hhi(u.w), acc[7]);
    }
  }
  #pragma unroll
  for (int k = 0; k < 8; ++k){
    acc[k] += __shfl_xor(acc[k], 16);
    acc[k] += __shfl_xor(acc[k], 32);
  }
  #pragma unroll
  for (int off = 32; off; off >>= 1) s += __shfl_xor(s, off);
  if (lane < 16){
    float rs = (deg > 0) ? 1.0f / s : 0.f;
    float4 o0 = make_float4(acc[0]*rs, acc[1]*rs, acc[2]*rs, acc[3]*rs);
    float4 o1 = make_float4(acc[4]*rs, acc[5]*rs, acc[6]*rs, acc[7]*rs);
    *(float4*)&out[(size_t)n*128 + l16*8]     = o0;
    *(float4*)&out[(size_t)n*128 + l16*8 + 4] = o1;
  }
}

// ---------------- host launch ----------------
static inline size_t align256(size_t x){ return (x + 255) & ~(size_t)255; }

extern "C" void kernel_launch(void* const* d_in, const int* in_sizes, int n_in,
                              void* d_out, int out_size, void* d_ws, size_t ws_size,
                              hipStream_t stream){
  const float* h_in = (const float*)d_in[0];
  const int*   src  = (const int*)d_in[1];
  const int*   dst  = (const int*)d_in[2];
  const float* W1   = (const float*)d_in[3];
  const float* al1  = (const float*)d_in[4];
  const float* ar1  = (const float*)d_in[5];
  const float* W2   = (const float*)d_in[6];
  const float* al2  = (const float*)d_in[7];
  const float* ar2  = (const float*)d_in[8];
  float* out = (float*)d_out;

  char* ws = (char*)d_ws;
  size_t off = 0;
  ushort* Ab     = (ushort*)(ws + off); off = align256(off + (size_t)NN*256*2);  // reused as h1b
  ushort* featb  = (ushort*)(ws + off); off = align256(off + (size_t)NN*256*2);
  ushort* feat2  = (ushort*)(ws + off); off = align256(off + (size_t)NN*128*2);  // f16
  float* el1     = (float*)(ws + off);  off = align256(off + (size_t)NN*4*4);
  float* er1     = (float*)(ws + off);  off = align256(off + (size_t)NN*4*4);
  int* rowptr    = (int*)(ws + off);    off = align256(off + (size_t)(NN+1)*4);
  int* cnt       = (int*)(ws + off);    off = align256(off + (size_t)NN*4);
  int* cursor    = (int*)(ws + off);    off = align256(off + (size_t)NN*4);
  int* csr_src   = (int*)(ws + off);    off = align256(off + (size_t)EE*4);
  ushort* Bth1   = (ushort*)(ws + off); off = align256(off + (size_t)256*256*2);
  ushort* Btl1   = (ushort*)(ws + off); off = align256(off + (size_t)256*256*2);
  ushort* Bth2   = (ushort*)(ws + off); off = align256(off + (size_t)128*256*2);
  ushort* Btl2   = (ushort*)(ws + off); off = align256(off + (size_t)128*256*2);
  int* bsum      = (int*)(ws + off);    off = align256(off + (size_t)64*4);
  int* boff      = (int*)(ws + off);    off = align256(off + (size_t)64*4);
  if (off > ws_size) return;  // fail loudly: output stays poisoned

  ushort* h1b = Ab;
  float* el2 = el1;
  float* er2 = er1;

  const int EB = (EE + 255)/256;
  const int FB = (NN + 3)/4;
  const int NB = (NN + 1023)/1024;
  const int MT = (NN + 127)/128;

  // CSR build
  hipMemsetAsync(cnt, 0, (size_t)NN*4, stream);
  k_hist<<<EB, 256, 0, stream>>>(dst, cnt, EE);
  k_scan_bsum<<<NB, 1024, 0, stream>>>(cnt, bsum, NN);
  k_scan_boff<<<1, 64, 0, stream>>>(bsum, boff, NB, rowptr, NN);
  k_scan_write<<<NB, 1024, 0, stream>>>(cnt, boff, rowptr, cursor, NN);
  k_scatter<<<EB, 256, 0, stream>>>(src, dst, cursor, csr_src, EE);

  // merged prep
  k_prep<<<13012, 256, 0, stream>>>(h_in, Ab, W1, Bth1, Btl1, W2, Bth2, Btl2);

  // ----- layer 1 -----
  k_mgemm<1><<<dim3(2, MT), 512, 0, stream>>>(Ab, Bth1, Btl1, featb, al1, ar1, el1, er1, NN, 256, 256);
  k_fused1<<<FB, 256, 0, stream>>>(rowptr, csr_src, el1, er1, featb, h1b);

  // ----- layer 2 -----
  k_mgemm<2><<<dim3(1, MT), 512, 0, stream>>>(h1b, Bth2, Btl2, feat2, al2, ar2, el2, er2, NN, 256, 128);
  k_fused2<<<FB, 256, 0, stream>>>(rowptr, csr_src, el2, er2, feat2, out);
}

// Round 11
// 247.122 us; speedup vs baseline: 1.0571x; 1.0300x over previous
//
#include <hip/hip_runtime.h>
#include <hip/hip_bf16.h>
#include <hip/hip_fp16.h>
#include <math.h>

#define NN 50000
#define EE 800000

__device__ __forceinline__ float lrelu(float v){ return v > 0.f ? v : 0.2f * v; }
__device__ __forceinline__ float sel4(float4 v, int h){
  return h == 0 ? v.x : h == 1 ? v.y : h == 2 ? v.z : v.w;
}
__device__ __forceinline__ ushort f2bf(float x){
  union { __hip_bfloat16 b; ushort u; } cv; cv.b = __float2bfloat16(x); return cv.u;
}
__device__ __forceinline__ float bf2f(ushort u){
  union { uint u; float f; } cv; cv.u = (uint)u << 16; return cv.f;
}
__device__ __forceinline__ ushort f2h(float x){
  union { __half h; ushort u; } cv; cv.h = __float2half(x); return cv.u;
}
// packed unpack helpers
__device__ __forceinline__ float bflo(uint u){ union{uint u; float f;} c; c.u = u << 16; return c.f; }
__device__ __forceinline__ float bfhi(uint u){ union{uint u; float f;} c; c.u = u & 0xffff0000u; return c.f; }
__device__ __forceinline__ float hlo(uint u){
  union{ ushort us; __half h; } c; c.us = (ushort)(u & 0xffffu); return __half2float(c.h);
}
__device__ __forceinline__ float hhi(uint u){
  union{ ushort us; __half h; } c; c.us = (ushort)(u >> 16); return __half2float(c.h);
}
// packed fp32 FMA: acc.x += f.x*a.x; acc.y += f.y*a.y  (one VALU instruction)
__device__ __forceinline__ void pkfma(float2 &acc, float2 f, float2 a){
  asm volatile("v_pk_fma_f32 %0, %1, %2, %0" : "+v"(acc) : "v"(f), "v"(a));
}

typedef __attribute__((ext_vector_type(8))) short bf16x8;
typedef __attribute__((ext_vector_type(4))) float f32x4;

// async global->LDS, 16B per lane
__device__ __forceinline__ void gload16(const ushort* g, ushort* l){
  const auto* gp = reinterpret_cast<const __attribute__((address_space(1))) ushort*>((size_t)g);
  auto* lp = reinterpret_cast<__attribute__((address_space(3))) ushort*>((size_t)l);
  __builtin_amdgcn_global_load_lds(gp, lp, 16, 0, 0);
}

// ---------------- CSR scan ----------------
__global__ __launch_bounds__(1024) void k_scan_bsum(const int* __restrict__ cnt, int* __restrict__ bsum, int n){
  __shared__ int ws[16];
  int t = threadIdx.x, i = blockIdx.x*1024 + t;
  int v = (i < n) ? cnt[i] : 0;
  #pragma unroll
  for (int off = 32; off; off >>= 1) v += __shfl_down(v, off);
  if ((t & 63) == 0) ws[t >> 6] = v;
  __syncthreads();
  if (t < 64){
    int x = (t < 16) ? ws[t] : 0;
    #pragma unroll
    for (int off = 32; off; off >>= 1) x += __shfl_down(x, off);
    if (t == 0) bsum[blockIdx.x] = x;
  }
}

__global__ void k_scan_boff(const int* __restrict__ bsum, int* __restrict__ boff,
                            int nb, int* __restrict__ rowptr, int n){
  int t = threadIdx.x;
  int v = (t < nb) ? bsum[t] : 0;
  int x = v;
  #pragma unroll
  for (int off = 1; off < 64; off <<= 1){ int y = __shfl_up(x, off); if (t >= off) x += y; }
  if (t < nb) boff[t] = x - v;
  if (t == 63) rowptr[n] = x;
}

__global__ __launch_bounds__(1024) void k_scan_write(const int* __restrict__ cnt, const int* __restrict__ boff,
                                                     int* __restrict__ rowptr, int* __restrict__ cursor, int n){
  __shared__ int ws[16];
  int t = threadIdx.x, w = t >> 6, lane = t & 63, i = blockIdx.x*1024 + t;
  int v = (i < n) ? cnt[i] : 0;
  int x = v;
  #pragma unroll
  for (int off = 1; off < 64; off <<= 1){ int y = __shfl_up(x, off); if (lane >= off) x += y; }
  if (lane == 63) ws[w] = x;
  __syncthreads();
  if (t < 16){
    int y = ws[t];
    #pragma unroll
    for (int off = 1; off < 16; off <<= 1){ int z = __shfl_up(y, off); if (t >= off) y += z; }
    ws[t] = y;
  }
  __syncthreads();
  if (i < n){
    int ex = boff[blockIdx.x] + ((w > 0) ? ws[w-1] : 0) + x - v;
    rowptr[i] = ex;
    cursor[i] = ex;
  }
}

__global__ void k_scatter(const int* __restrict__ src, const int* __restrict__ dst,
                          int* __restrict__ cursor, int* __restrict__ csr_src, int E){
  int i = blockIdx.x * blockDim.x + threadIdx.x;
  if (i < E){ int p = atomicAdd(&cursor[dst[i]], 1); csr_src[p] = src[i]; }
}

// ---------------- merged prep + hist ----------------
// blocks [0,12500): A->bf16 ; [12500,12756): W1 ; [12756,13012): W2 ;
// [13012,16137): dst histogram (3125 blocks x 256 = 800000)
__global__ void k_prep(const float* __restrict__ A, ushort* __restrict__ Ab,
                       const float* __restrict__ W1, ushort* __restrict__ Bth1, ushort* __restrict__ Btl1,
                       const float* __restrict__ W2, ushort* __restrict__ Bth2, ushort* __restrict__ Btl2,
                       const int* __restrict__ dst, int* __restrict__ cnt){
  int b = blockIdx.x, t = threadIdx.x;
  if (b < 12500){
    int i = b*256 + t;
    float4 v = ((const float4*)A)[i];
    ((ushort4*)Ab)[i] = make_ushort4(f2bf(v.x), f2bf(v.y), f2bf(v.z), f2bf(v.w));
  } else if (b < 12756){
    int k = b - 12500;
    float x = W1[(size_t)k*256 + t];
    ushort h = f2bf(x);
    Bth1[(size_t)t*256 + k] = h;
    Btl1[(size_t)t*256 + k] = f2bf(x - bf2f(h));
  } else if (b < 13012){
    int k = b - 12756;
    if (t < 128){
      float x = W2[(size_t)k*128 + t];
      ushort h = f2bf(x);
      Bth2[(size_t)t*256 + k] = h;
      Btl2[(size_t)t*256 + k] = f2bf(x - bf2f(h));
    }
  } else {
    int i = (b - 13012)*256 + t;          // < 800000 exactly
    atomicAdd(&cnt[dst[i]], 1);
  }
}

// ---------------- bf16-A x split-bf16-B MFMA GEMM + fused el/er epilogue ----------------
template<int MODE>
__global__ __launch_bounds__(512, 4) void k_mgemm(
    const ushort* __restrict__ Ab,
    const ushort* __restrict__ Bth, const ushort* __restrict__ Btl,
    void* __restrict__ Cout, const float* __restrict__ avl, const float* __restrict__ avr,
    float* __restrict__ el, float* __restrict__ er, int M, int K, int N)
{
  __shared__ __align__(16) ushort sA[2][128*32];
  __shared__ __align__(16) ushort sBh[2][128*32];
  __shared__ __align__(16) ushort sBl[2][128*32];
  __shared__ float sEL[2][128], sER[2][128];
  int tid = threadIdx.x;
  int w = tid >> 6, lane = tid & 63;
  int bm = blockIdx.y*128, bn = blockIdx.x*128;
  int wm = (w & 3)*32, wn = (w >> 2)*64;
  int fr = lane & 15, fg = lane >> 4;

  int srow = 16*w + (lane >> 2);
  int skoff = (lane & 3)*8;
  int arow = bm + srow; if (arow > M-1) arow = M-1;
  const ushort* gA  = Ab  + (size_t)arow*K + skoff;
  const ushort* gBh = Bth + (size_t)(bn + srow)*K + skoff;
  const ushort* gBl = Btl + (size_t)(bn + srow)*K + skoff;
  int lslice = 16*w*32;

  const int nk = K >> 5;
  gload16(gA,  &sA[0][lslice]);
  gload16(gBh, &sBh[0][lslice]);
  gload16(gBl, &sBl[0][lslice]);
  __syncthreads();

  f32x4 acc[2][4] = {};
  for (int kt = 0; kt < nk; ++kt){
    int buf = kt & 1;
    if (kt + 1 < nk){
      int k1 = (kt + 1) << 5;
      gload16(gA + k1,  &sA[buf^1][lslice]);
      gload16(gBh + k1, &sBh[buf^1][lslice]);
      gload16(gBl + k1, &sBl[buf^1][lslice]);
    }
    bf16x8 ah[2], bh[4], bl[4];
    #pragma unroll
    for (int ti = 0; ti < 2; ++ti)
      ah[ti] = *(const bf16x8*)&sA[buf][(wm + ti*16 + fr)*32 + fg*8];
    #pragma unroll
    for (int tj = 0; tj < 4; ++tj){
      int bi = (wn + tj*16 + fr)*32 + fg*8;
      bh[tj] = *(const bf16x8*)&sBh[buf][bi];
      bl[tj] = *(const bf16x8*)&sBl[buf][bi];
    }
    #pragma unroll
    for (int ti = 0; ti < 2; ++ti)
      #pragma unroll
      for (int tj = 0; tj < 4; ++tj){
        acc[ti][tj] = __builtin_amdgcn_mfma_f32_16x16x32_bf16(ah[ti], bh[tj], acc[ti][tj], 0,0,0);
        acc[ti][tj] = __builtin_amdgcn_mfma_f32_16x16x32_bf16(ah[ti], bl[tj], acc[ti][tj], 0,0,0);
      }
    __syncthreads();
  }

  int colhead = bn + wn;
  float wl[4], wr[4];
  #pragma unroll
  for (int tj = 0; tj < 4; ++tj){
    int c = colhead + tj*16 + fr;
    wl[tj] = avl[c]; wr[tj] = avr[c];
  }
  #pragma unroll
  for (int ti = 0; ti < 2; ++ti)
    #pragma unroll
    for (int i = 0; i < 4; ++i){
      int row = bm + wm + ti*16 + fg*4 + i;
      float pl = 0.f, pr = 0.f;
      #pragma unroll
      for (int tj = 0; tj < 4; ++tj){
        float v = acc[ti][tj][i];
        pl = fmaf(v, wl[tj], pl);
        pr = fmaf(v, wr[tj], pr);
        if (row < M){
          int col = colhead + tj*16 + fr;
          if (MODE == 1) ((ushort*)Cout)[(size_t)row*256 + col] = f2bf(v);
          else           ((ushort*)Cout)[(size_t)row*128 + col] = f2h(v);
        }
      }
      #pragma unroll
      for (int mk = 1; mk < 16; mk <<= 1){
        pl += __shfl_xor(pl, mk);
        pr += __shfl_xor(pr, mk);
      }
      if (fr == 0){
        if (MODE == 1){
          if (row < M){ el[row*4 + (colhead >> 6)] = pl; er[row*4 + (colhead >> 6)] = pr; }
        } else {
          int lr = wm + ti*16 + fg*4 + i;
          sEL[w >> 2][lr] = pl; sER[w >> 2][lr] = pr;
        }
      }
    }
  if (MODE == 2){
    __syncthreads();
    if (tid < 128){
      int row = bm + tid;
      if (row < M){
        el[row] = sEL[0][tid] + sEL[1][tid];
        er[row] = sER[0][tid] + sER[1][tid];
      }
    }
  }
}

// ---------------- fused softmax+aggregate, layer 1 ----------------
// Wave per node; half-wave (32 x 16B) reads a full 512B bf16 row -> 2 edges/VMEM.
// Aggregation via v_pk_fma_f32 on packed {lo,hi} pairs.
__global__ __launch_bounds__(256) void k_fused1(
    const int* __restrict__ rowptr, const int* __restrict__ csr_src,
    const float* __restrict__ el, const float* __restrict__ er,
    const ushort* __restrict__ featb, ushort* __restrict__ h1b)
{
  __shared__ __align__(16) float p_sh[4][64*4];
  __shared__ int si_sh[4][64];
  int w = threadIdx.x >> 6, lane = threadIdx.x & 63;
  int n = blockIdx.x*4 + w;
  if (n >= NN) return;
  int b = rowptr[n], deg = rowptr[n+1] - b;
  int l32 = lane & 31, half = lane >> 5;
  int h = l32 >> 3;
  float4 er4 = *(const float4*)&er[n*4];
  float4 s4 = make_float4(0,0,0,0);
  float2 a0 = make_float2(0.f,0.f), a1 = a0, a2 = a0, a3 = a0;

  for (int c0 = 0; c0 < deg; c0 += 64){
    int C = min(64, deg - c0);
    int si = 0;
    float4 p4 = make_float4(0,0,0,0);
    if (lane < C){
      si = csr_src[b + c0 + lane];
      float4 l4 = *(const float4*)&el[si*4];
      p4.x = __expf(lrelu(l4.x + er4.x));
      p4.y = __expf(lrelu(l4.y + er4.y));
      p4.z = __expf(lrelu(l4.z + er4.z));
      p4.w = __expf(lrelu(l4.w + er4.w));
    }
    s4.x += p4.x; s4.y += p4.y; s4.z += p4.z; s4.w += p4.w;
    *(float4*)&p_sh[w][lane*4] = p4;       // zero-pads beyond C
    si_sh[w][lane] = si;
    #pragma unroll 8
    for (int j = 0; j < C; j += 2){
      int e = j + half;
      float a = p_sh[w][e*4 + h];
      int sj = si_sh[w][e];
      uint4 u = *(const uint4*)&featb[(size_t)sj*256 + l32*8];
      float2 aa = make_float2(a, a);
      pkfma(a0, make_float2(bflo(u.x), bfhi(u.x)), aa);
      pkfma(a1, make_float2(bflo(u.y), bfhi(u.y)), aa);
      pkfma(a2, make_float2(bflo(u.z), bfhi(u.z)), aa);
      pkfma(a3, make_float2(bflo(u.w), bfhi(u.w)), aa);
    }
  }
  // combine half-wave partials
  a0.x += __shfl_xor(a0.x, 32); a0.y += __shfl_xor(a0.y, 32);
  a1.x += __shfl_xor(a1.x, 32); a1.y += __shfl_xor(a1.y, 32);
  a2.x += __shfl_xor(a2.x, 32); a2.y += __shfl_xor(a2.y, 32);
  a3.x += __shfl_xor(a3.x, 32); a3.y += __shfl_xor(a3.y, 32);
  // denominator reduce
  #pragma unroll
  for (int off = 32; off; off >>= 1){
    s4.x += __shfl_xor(s4.x, off); s4.y += __shfl_xor(s4.y, off);
    s4.z += __shfl_xor(s4.z, off); s4.w += __shfl_xor(s4.w, off);
  }
  if (lane < 32){
    float rs = (deg > 0) ? 1.0f / sel4(s4, h) : 0.f;
    float vv[8] = {a0.x, a0.y, a1.x, a1.y, a2.x, a2.y, a3.x, a3.y};
    ushort ob[8];
    #pragma unroll
    for (int k = 0; k < 8; ++k){
      float v = vv[k] * rs;
      v = (v > 0.f) ? v : (__expf(v) - 1.f);
      ob[k] = f2bf(v);
    }
    uint4 pk;
    pk.x = (uint)ob[0] | ((uint)ob[1] << 16);
    pk.y = (uint)ob[2] | ((uint)ob[3] << 16);
    pk.z = (uint)ob[4] | ((uint)ob[5] << 16);
    pk.w = (uint)ob[6] | ((uint)ob[7] << 16);
    *(uint4*)&h1b[(size_t)n*256 + l32*8] = pk;
  }
}

// ---------------- fused softmax+aggregate, layer 2 ----------------
// Wave per node; 16-lane group (16 x 16B) reads a full 256B f16 row -> 4 edges/VMEM.
__global__ __launch_bounds__(256) void k_fused2(
    const int* __restrict__ rowptr, const int* __restrict__ csr_src,
    const float* __restrict__ el, const float* __restrict__ er,
    const ushort* __restrict__ featH, float* __restrict__ out)
{
  __shared__ float p_sh[4][64];
  __shared__ int si_sh[4][64];
  int w = threadIdx.x >> 6, lane = threadIdx.x & 63;
  int n = blockIdx.x*4 + w;
  if (n >= NN) return;
  int b = rowptr[n], deg = rowptr[n+1] - b;
  int l16 = lane & 15, grp = lane >> 4;
  float er_n = er[n];
  float s = 0.f;
  float2 a0 = make_float2(0.f,0.f), a1 = a0, a2 = a0, a3 = a0;

  for (int c0 = 0; c0 < deg; c0 += 64){
    int C = min(64, deg - c0);
    int si = 0;
    float p = 0.f;
    if (lane < C){
      si = csr_src[b + c0 + lane];
      p = __expf(lrelu(el[si] + er_n));
    }
    s += p;
    p_sh[w][lane] = p;
    si_sh[w][lane] = si;
    #pragma unroll 8
    for (int j = 0; j < C; j += 4){
      int e = j + grp;
      float a = p_sh[w][e];
      int sj = si_sh[w][e];
      uint4 u = *(const uint4*)&featH[(size_t)sj*128 + l16*8];
      float2 aa = make_float2(a, a);
      pkfma(a0, make_float2(hlo(u.x), hhi(u.x)), aa);
      pkfma(a1, make_float2(hlo(u.y), hhi(u.y)), aa);
      pkfma(a2, make_float2(hlo(u.z), hhi(u.z)), aa);
      pkfma(a3, make_float2(hlo(u.w), hhi(u.w)), aa);
    }
  }
  float acc[8] = {a0.x, a0.y, a1.x, a1.y, a2.x, a2.y, a3.x, a3.y};
  #pragma unroll
  for (int k = 0; k < 8; ++k){
    acc[k] += __shfl_xor(acc[k], 16);
    acc[k] += __shfl_xor(acc[k], 32);
  }
  #pragma unroll
  for (int off = 32; off; off >>= 1) s += __shfl_xor(s, off);
  if (lane < 16){
    float rs = (deg > 0) ? 1.0f / s : 0.f;
    float4 o0 = make_float4(acc[0]*rs, acc[1]*rs, acc[2]*rs, acc[3]*rs);
    float4 o1 = make_float4(acc[4]*rs, acc[5]*rs, acc[6]*rs, acc[7]*rs);
    *(float4*)&out[(size_t)n*128 + l16*8]     = o0;
    *(float4*)&out[(size_t)n*128 + l16*8 + 4] = o1;
  }
}

// ---------------- host launch ----------------
static inline size_t align256(size_t x){ return (x + 255) & ~(size_t)255; }

extern "C" void kernel_launch(void* const* d_in, const int* in_sizes, int n_in,
                              void* d_out, int out_size, void* d_ws, size_t ws_size,
                              hipStream_t stream){
  const float* h_in = (const float*)d_in[0];
  const int*   src  = (const int*)d_in[1];
  const int*   dst  = (const int*)d_in[2];
  const float* W1   = (const float*)d_in[3];
  const float* al1  = (const float*)d_in[4];
  const float* ar1  = (const float*)d_in[5];
  const float* W2   = (const float*)d_in[6];
  const float* al2  = (const float*)d_in[7];
  const float* ar2  = (const float*)d_in[8];
  float* out = (float*)d_out;

  char* ws = (char*)d_ws;
  size_t off = 0;
  ushort* Ab     = (ushort*)(ws + off); off = align256(off + (size_t)NN*256*2);  // reused as h1b
  ushort* featb  = (ushort*)(ws + off); off = align256(off + (size_t)NN*256*2);
  ushort* feat2  = (ushort*)(ws + off); off = align256(off + (size_t)NN*128*2);  // f16
  float* el1     = (float*)(ws + off);  off = align256(off + (size_t)NN*4*4);
  float* er1     = (float*)(ws + off);  off = align256(off + (size_t)NN*4*4);
  int* rowptr    = (int*)(ws + off);    off = align256(off + (size_t)(NN+1)*4);
  int* cnt       = (int*)(ws + off);    off = align256(off + (size_t)NN*4);
  int* cursor    = (int*)(ws + off);    off = align256(off + (size_t)NN*4);
  int* csr_src   = (int*)(ws + off);    off = align256(off + (size_t)EE*4);
  ushort* Bth1   = (ushort*)(ws + off); off = align256(off + (size_t)256*256*2);
  ushort* Btl1   = (ushort*)(ws + off); off = align256(off + (size_t)256*256*2);
  ushort* Bth2   = (ushort*)(ws + off); off = align256(off + (size_t)128*256*2);
  ushort* Btl2   = (ushort*)(ws + off); off = align256(off + (size_t)128*256*2);
  int* bsum      = (int*)(ws + off);    off = align256(off + (size_t)64*4);
  int* boff      = (int*)(ws + off);    off = align256(off + (size_t)64*4);
  if (off > ws_size) return;  // fail loudly: output stays poisoned

  ushort* h1b = Ab;
  float* el2 = el1;
  float* er2 = er1;

  const int EB = (EE + 255)/256;
  const int FB = (NN + 3)/4;
  const int NB = (NN + 1023)/1024;
  const int MT = (NN + 127)/128;

  // memset + merged prep/hist, then CSR chain
  hipMemsetAsync(cnt, 0, (size_t)NN*4, stream);
  k_prep<<<13012 + EB, 256, 0, stream>>>(h_in, Ab, W1, Bth1, Btl1, W2, Bth2, Btl2, dst, cnt);
  k_scan_bsum<<<NB, 1024, 0, stream>>>(cnt, bsum, NN);
  k_scan_boff<<<1, 64, 0, stream>>>(bsum, boff, NB, rowptr, NN);
  k_scan_write<<<NB, 1024, 0, stream>>>(cnt, boff, rowptr, cursor, NN);
  k_scatter<<<EB, 256, 0, stream>>>(src, dst, cursor, csr_src, EE);

  // ----- layer 1 -----
  k_mgemm<1><<<dim3(2, MT), 512, 0, stream>>>(Ab, Bth1, Btl1, featb, al1, ar1, el1, er1, NN, 256, 256);
  k_fused1<<<FB, 256, 0, stream>>>(rowptr, csr_src, el1, er1, featb, h1b);

  // ----- layer 2 -----
  k_mgemm<2><<<dim3(1, MT), 512, 0, stream>>>(h1b, Bth2, Btl2, feat2, al2, ar2, el2, er2, NN, 256, 128);
  k_fused2<<<FB, 256, 0, stream>>>(rowptr, csr_src, el2, er2, feat2, out);
}

// Round 12
// 242.988 us; speedup vs baseline: 1.0750x; 1.0170x over previous
//
#include <hip/hip_runtime.h>
#include <hip/hip_bf16.h>
#include <hip/hip_fp16.h>
#include <math.h>

#define NN 50000
#define EE 800000
#define NB_SCAN 49   // ceil(NN/1024)

__device__ __forceinline__ float lrelu(float v){ return v > 0.f ? v : 0.2f * v; }
__device__ __forceinline__ float sel4(float4 v, int h){
  return h == 0 ? v.x : h == 1 ? v.y : h == 2 ? v.z : v.w;
}
__device__ __forceinline__ ushort f2bf(float x){
  union { __hip_bfloat16 b; ushort u; } cv; cv.b = __float2bfloat16(x); return cv.u;
}
__device__ __forceinline__ float bf2f(ushort u){
  union { uint u; float f; } cv; cv.u = (uint)u << 16; return cv.f;
}
__device__ __forceinline__ ushort f2h(float x){
  union { __half h; ushort u; } cv; cv.h = __float2half(x); return cv.u;
}
__device__ __forceinline__ float bflo(uint u){ union{uint u; float f;} c; c.u = u << 16; return c.f; }
__device__ __forceinline__ float bfhi(uint u){ union{uint u; float f;} c; c.u = u & 0xffff0000u; return c.f; }
__device__ __forceinline__ float hlo(uint u){
  union{ ushort us; __half h; } c; c.us = (ushort)(u & 0xffffu); return __half2float(c.h);
}
__device__ __forceinline__ float hhi(uint u){
  union{ ushort us; __half h; } c; c.us = (ushort)(u >> 16); return __half2float(c.h);
}
__device__ __forceinline__ void pkfma(float2 &acc, float2 f, float2 a){
  asm volatile("v_pk_fma_f32 %0, %1, %2, %0" : "+v"(acc) : "v"(f), "v"(a));
}

typedef __attribute__((ext_vector_type(8))) short bf16x8;
typedef __attribute__((ext_vector_type(4))) float f32x4;

__device__ __forceinline__ void gload16(const ushort* g, ushort* l){
  const auto* gp = reinterpret_cast<const __attribute__((address_space(1))) ushort*>((size_t)g);
  auto* lp = reinterpret_cast<__attribute__((address_space(3))) ushort*>((size_t)l);
  __builtin_amdgcn_global_load_lds(gp, lp, 16, 0, 0);
}

// ---------------- CSR scan ----------------
__global__ __launch_bounds__(1024) void k_scan_bsum(const int* __restrict__ cnt, int* __restrict__ bsum, int n){
  __shared__ int ws[16];
  int t = threadIdx.x, i = blockIdx.x*1024 + t;
  int v = (i < n) ? cnt[i] : 0;
  #pragma unroll
  for (int off = 32; off; off >>= 1) v += __shfl_down(v, off);
  if ((t & 63) == 0) ws[t >> 6] = v;
  __syncthreads();
  if (t < 64){
    int x = (t < 16) ? ws[t] : 0;
    #pragma unroll
    for (int off = 32; off; off >>= 1) x += __shfl_down(x, off);
    if (t == 0) bsum[blockIdx.x] = x;
  }
}

// merged: per-block redundant scan of bsum (one wave) + intra-block scan + write
__global__ __launch_bounds__(1024) void k_scan_write(const int* __restrict__ cnt, const int* __restrict__ bsum,
                                                     int* __restrict__ rowptr, int* __restrict__ cursor, int n){
  __shared__ int ws[16];
  __shared__ int s_boff;
  int t = threadIdx.x, w = t >> 6, lane = t & 63, i = blockIdx.x*1024 + t;
  // wave 0: exclusive-scan bsum[0..NB_SCAN-1] redundantly
  if (t < 64){
    int v = (t < NB_SCAN) ? bsum[t] : 0;
    int x = v;
    #pragma unroll
    for (int off = 1; off < 64; off <<= 1){ int y = __shfl_up(x, off); if (t >= off) x += y; }
    if (t == (uint)blockIdx.x) s_boff = x - v;
    if (blockIdx.x == 0 && t == 63) rowptr[n] = x;   // grand total
  }
  int v = (i < n) ? cnt[i] : 0;
  int x = v;
  #pragma unroll
  for (int off = 1; off < 64; off <<= 1){ int y = __shfl_up(x, off); if (lane >= off) x += y; }
  if (lane == 63) ws[w] = x;
  __syncthreads();
  if (t < 16){
    int y = ws[t];
    #pragma unroll
    for (int off = 1; off < 16; off <<= 1){ int z = __shfl_up(y, off); if (t >= off) y += z; }
    ws[t] = y;
  }
  __syncthreads();
  if (i < n){
    int ex = s_boff + ((w > 0) ? ws[w-1] : 0) + x - v;
    rowptr[i] = ex;
    cursor[i] = ex;
  }
}

__global__ void k_scatter(const int* __restrict__ src, const int* __restrict__ dst,
                          int* __restrict__ cursor, int* __restrict__ csr_src, int E){
  int i = blockIdx.x * blockDim.x + threadIdx.x;
  if (i < E){ int p = atomicAdd(&cursor[dst[i]], 1); csr_src[p] = src[i]; }
}

// ---------------- merged prep + hist ----------------
// blocks [0,6250): A->bf16 (2 float4/thread) ; [6250,6506): W1 ; [6506,6762): W2 ;
// [6762,9887): dst histogram (3125 x 256 = 800000)
__global__ void k_prep(const float* __restrict__ A, ushort* __restrict__ Ab,
                       const float* __restrict__ W1, ushort* __restrict__ Bth1, ushort* __restrict__ Btl1,
                       const float* __restrict__ W2, ushort* __restrict__ Bth2, ushort* __restrict__ Btl2,
                       const int* __restrict__ dst, int* __restrict__ cnt){
  int b = blockIdx.x, t = threadIdx.x;
  if (b < 6250){
    int i = b*512 + t;
    float4 v0 = ((const float4*)A)[i];
    float4 v1 = ((const float4*)A)[i + 256];
    ((ushort4*)Ab)[i]       = make_ushort4(f2bf(v0.x), f2bf(v0.y), f2bf(v0.z), f2bf(v0.w));
    ((ushort4*)Ab)[i + 256] = make_ushort4(f2bf(v1.x), f2bf(v1.y), f2bf(v1.z), f2bf(v1.w));
  } else if (b < 6506){
    int k = b - 6250;
    float x = W1[(size_t)k*256 + t];
    ushort h = f2bf(x);
    Bth1[(size_t)t*256 + k] = h;
    Btl1[(size_t)t*256 + k] = f2bf(x - bf2f(h));
  } else if (b < 6762){
    int k = b - 6506;
    if (t < 128){
      float x = W2[(size_t)k*128 + t];
      ushort h = f2bf(x);
      Bth2[(size_t)t*256 + k] = h;
      Btl2[(size_t)t*256 + k] = f2bf(x - bf2f(h));
    }
  } else {
    int i = (b - 6762)*256 + t;          // < 800000 exactly
    atomicAdd(&cnt[dst[i]], 1);
  }
}

// ---------------- bf16-A x split-bf16-B MFMA GEMM + fused el/er epilogue ----------------
template<int MODE>
__global__ __launch_bounds__(512, 4) void k_mgemm(
    const ushort* __restrict__ Ab,
    const ushort* __restrict__ Bth, const ushort* __restrict__ Btl,
    void* __restrict__ Cout, const float* __restrict__ avl, const float* __restrict__ avr,
    float* __restrict__ el, float* __restrict__ er, int M, int K, int N)
{
  __shared__ __align__(16) ushort sA[2][128*32];
  __shared__ __align__(16) ushort sBh[2][128*32];
  __shared__ __align__(16) ushort sBl[2][128*32];
  __shared__ float sEL[2][128], sER[2][128];
  int tid = threadIdx.x;
  int w = tid >> 6, lane = tid & 63;
  int bm = blockIdx.y*128, bn = blockIdx.x*128;
  int wm = (w & 3)*32, wn = (w >> 2)*64;
  int fr = lane & 15, fg = lane >> 4;

  int srow = 16*w + (lane >> 2);
  int skoff = (lane & 3)*8;
  int arow = bm + srow; if (arow > M-1) arow = M-1;
  const ushort* gA  = Ab  + (size_t)arow*K + skoff;
  const ushort* gBh = Bth + (size_t)(bn + srow)*K + skoff;
  const ushort* gBl = Btl + (size_t)(bn + srow)*K + skoff;
  int lslice = 16*w*32;

  const int nk = K >> 5;
  gload16(gA,  &sA[0][lslice]);
  gload16(gBh, &sBh[0][lslice]);
  gload16(gBl, &sBl[0][lslice]);
  __syncthreads();

  f32x4 acc[2][4] = {};
  for (int kt = 0; kt < nk; ++kt){
    int buf = kt & 1;
    if (kt + 1 < nk){
      int k1 = (kt + 1) << 5;
      gload16(gA + k1,  &sA[buf^1][lslice]);
      gload16(gBh + k1, &sBh[buf^1][lslice]);
      gload16(gBl + k1, &sBl[buf^1][lslice]);
    }
    bf16x8 ah[2], bh[4], bl[4];
    #pragma unroll
    for (int ti = 0; ti < 2; ++ti)
      ah[ti] = *(const bf16x8*)&sA[buf][(wm + ti*16 + fr)*32 + fg*8];
    #pragma unroll
    for (int tj = 0; tj < 4; ++tj){
      int bi = (wn + tj*16 + fr)*32 + fg*8;
      bh[tj] = *(const bf16x8*)&sBh[buf][bi];
      bl[tj] = *(const bf16x8*)&sBl[buf][bi];
    }
    #pragma unroll
    for (int ti = 0; ti < 2; ++ti)
      #pragma unroll
      for (int tj = 0; tj < 4; ++tj){
        acc[ti][tj] = __builtin_amdgcn_mfma_f32_16x16x32_bf16(ah[ti], bh[tj], acc[ti][tj], 0,0,0);
        acc[ti][tj] = __builtin_amdgcn_mfma_f32_16x16x32_bf16(ah[ti], bl[tj], acc[ti][tj], 0,0,0);
      }
    __syncthreads();
  }

  int colhead = bn + wn;
  float wl[4], wr[4];
  #pragma unroll
  for (int tj = 0; tj < 4; ++tj){
    int c = colhead + tj*16 + fr;
    wl[tj] = avl[c]; wr[tj] = avr[c];
  }
  #pragma unroll
  for (int ti = 0; ti < 2; ++ti)
    #pragma unroll
    for (int i = 0; i < 4; ++i){
      int row = bm + wm + ti*16 + fg*4 + i;
      float pl = 0.f, pr = 0.f;
      #pragma unroll
      for (int tj = 0; tj < 4; ++tj){
        float v = acc[ti][tj][i];
        pl = fmaf(v, wl[tj], pl);
        pr = fmaf(v, wr[tj], pr);
        if (row < M){
          int col = colhead + tj*16 + fr;
          if (MODE == 1) ((ushort*)Cout)[(size_t)row*256 + col] = f2bf(v);
          else           ((ushort*)Cout)[(size_t)row*128 + col] = f2h(v);
        }
      }
      #pragma unroll
      for (int mk = 1; mk < 16; mk <<= 1){
        pl += __shfl_xor(pl, mk);
        pr += __shfl_xor(pr, mk);
      }
      if (fr == 0){
        if (MODE == 1){
          if (row < M){ el[row*4 + (colhead >> 6)] = pl; er[row*4 + (colhead >> 6)] = pr; }
        } else {
          int lr = wm + ti*16 + fg*4 + i;
          sEL[w >> 2][lr] = pl; sER[w >> 2][lr] = pr;
        }
      }
    }
  if (MODE == 2){
    __syncthreads();
    if (tid < 128){
      int row = bm + tid;
      if (row < M){
        el[row] = sEL[0][tid] + sEL[1][tid];
        er[row] = sER[0][tid] + sER[1][tid];
      }
    }
  }
}

// ---------------- fused softmax+aggregate, layer 1 ----------------
__global__ __launch_bounds__(256) void k_fused1(
    const int* __restrict__ rowptr, const int* __restrict__ csr_src,
    const float* __restrict__ el, const float* __restrict__ er,
    const ushort* __restrict__ featb, ushort* __restrict__ h1b)
{
  __shared__ __align__(16) float p_sh[4][64*4];
  __shared__ int si_sh[4][64];
  int w = threadIdx.x >> 6, lane = threadIdx.x & 63;
  int n = blockIdx.x*4 + w;
  if (n >= NN) return;
  int b = rowptr[n], deg = rowptr[n+1] - b;
  int l32 = lane & 31, half = lane >> 5;
  int h = l32 >> 3;
  float4 er4 = *(const float4*)&er[n*4];
  float4 s4 = make_float4(0,0,0,0);
  float2 a0 = make_float2(0.f,0.f), a1 = a0, a2 = a0, a3 = a0;

  for (int c0 = 0; c0 < deg; c0 += 64){
    int C = min(64, deg - c0);
    int si = 0;
    float4 p4 = make_float4(0,0,0,0);
    if (lane < C){
      si = csr_src[b + c0 + lane];
      float4 l4 = *(const float4*)&el[si*4];
      p4.x = __expf(lrelu(l4.x + er4.x));
      p4.y = __expf(lrelu(l4.y + er4.y));
      p4.z = __expf(lrelu(l4.z + er4.z));
      p4.w = __expf(lrelu(l4.w + er4.w));
    }
    s4.x += p4.x; s4.y += p4.y; s4.z += p4.z; s4.w += p4.w;
    *(float4*)&p_sh[w][lane*4] = p4;
    si_sh[w][lane] = si;
    #pragma unroll 8
    for (int j = 0; j < C; j += 2){
      int e = j + half;
      float a = p_sh[w][e*4 + h];
      int sj = si_sh[w][e];
      uint4 u = *(const uint4*)&featb[(size_t)sj*256 + l32*8];
      float2 aa = make_float2(a, a);
      pkfma(a0, make_float2(bflo(u.x), bfhi(u.x)), aa);
      pkfma(a1, make_float2(bflo(u.y), bfhi(u.y)), aa);
      pkfma(a2, make_float2(bflo(u.z), bfhi(u.z)), aa);
      pkfma(a3, make_float2(bflo(u.w), bfhi(u.w)), aa);
    }
  }
  a0.x += __shfl_xor(a0.x, 32); a0.y += __shfl_xor(a0.y, 32);
  a1.x += __shfl_xor(a1.x, 32); a1.y += __shfl_xor(a1.y, 32);
  a2.x += __shfl_xor(a2.x, 32); a2.y += __shfl_xor(a2.y, 32);
  a3.x += __shfl_xor(a3.x, 32); a3.y += __shfl_xor(a3.y, 32);
  #pragma unroll
  for (int off = 32; off; off >>= 1){
    s4.x += __shfl_xor(s4.x, off); s4.y += __shfl_xor(s4.y, off);
    s4.z += __shfl_xor(s4.z, off); s4.w += __shfl_xor(s4.w, off);
  }
  if (lane < 32){
    float rs = (deg > 0) ? 1.0f / sel4(s4, h) : 0.f;
    float vv[8] = {a0.x, a0.y, a1.x, a1.y, a2.x, a2.y, a3.x, a3.y};
    ushort ob[8];
    #pragma unroll
    for (int k = 0; k < 8; ++k){
      float v = vv[k] * rs;
      v = (v > 0.f) ? v : (__expf(v) - 1.f);
      ob[k] = f2bf(v);
    }
    uint4 pk;
    pk.x = (uint)ob[0] | ((uint)ob[1] << 16);
    pk.y = (uint)ob[2] | ((uint)ob[3] << 16);
    pk.z = (uint)ob[4] | ((uint)ob[5] << 16);
    pk.w = (uint)ob[6] | ((uint)ob[7] << 16);
    *(uint4*)&h1b[(size_t)n*256 + l32*8] = pk;
  }
}

// ---------------- fused softmax+aggregate, layer 2 ----------------
__global__ __launch_bounds__(256) void k_fused2(
    const int* __restrict__ rowptr, const int* __restrict__ csr_src,
    const float* __restrict__ el, const float* __restrict__ er,
    const ushort* __restrict__ featH, float* __restrict__ out)
{
  __shared__ float p_sh[4][64];
  __shared__ int si_sh[4][64];
  int w = threadIdx.x >> 6, lane = threadIdx.x & 63;
  int n = blockIdx.x*4 + w;
  if (n >= NN) return;
  int b = rowptr[n], deg = rowptr[n+1] - b;
  int l16 = lane & 15, grp = lane >> 4;
  float er_n = er[n];
  float s = 0.f;
  float2 a0 = make_float2(0.f,0.f), a1 = a0, a2 = a0, a3 = a0;

  for (int c0 = 0; c0 < deg; c0 += 64){
    int C = min(64, deg - c0);
    int si = 0;
    float p = 0.f;
    if (lane < C){
      si = csr_src[b + c0 + lane];
      p = __expf(lrelu(el[si] + er_n));
    }
    s += p;
    p_sh[w][lane] = p;
    si_sh[w][lane] = si;
    #pragma unroll 8
    for (int j = 0; j < C; j += 4){
      int e = j + grp;
      float a = p_sh[w][e];
      int sj = si_sh[w][e];
      uint4 u = *(const uint4*)&featH[(size_t)sj*128 + l16*8];
      float2 aa = make_float2(a, a);
      pkfma(a0, make_float2(hlo(u.x), hhi(u.x)), aa);
      pkfma(a1, make_float2(hlo(u.y), hhi(u.y)), aa);
      pkfma(a2, make_float2(hlo(u.z), hhi(u.z)), aa);
      pkfma(a3, make_float2(hlo(u.w), hhi(u.w)), aa);
    }
  }
  float acc[8] = {a0.x, a0.y, a1.x, a1.y, a2.x, a2.y, a3.x, a3.y};
  #pragma unroll
  for (int k = 0; k < 8; ++k){
    acc[k] += __shfl_xor(acc[k], 16);
    acc[k] += __shfl_xor(acc[k], 32);
  }
  #pragma unroll
  for (int off = 32; off; off >>= 1) s += __shfl_xor(s, off);
  if (lane < 16){
    float rs = (deg > 0) ? 1.0f / s : 0.f;
    float4 o0 = make_float4(acc[0]*rs, acc[1]*rs, acc[2]*rs, acc[3]*rs);
    float4 o1 = make_float4(acc[4]*rs, acc[5]*rs, acc[6]*rs, acc[7]*rs);
    *(float4*)&out[(size_t)n*128 + l16*8]     = o0;
    *(float4*)&out[(size_t)n*128 + l16*8 + 4] = o1;
  }
}

// ---------------- host launch ----------------
static inline size_t align256(size_t x){ return (x + 255) & ~(size_t)255; }

extern "C" void kernel_launch(void* const* d_in, const int* in_sizes, int n_in,
                              void* d_out, int out_size, void* d_ws, size_t ws_size,
                              hipStream_t stream){
  const float* h_in = (const float*)d_in[0];
  const int*   src  = (const int*)d_in[1];
  const int*   dst  = (const int*)d_in[2];
  const float* W1   = (const float*)d_in[3];
  const float* al1  = (const float*)d_in[4];
  const float* ar1  = (const float*)d_in[5];
  const float* W2   = (const float*)d_in[6];
  const float* al2  = (const float*)d_in[7];
  const float* ar2  = (const float*)d_in[8];
  float* out = (float*)d_out;

  char* ws = (char*)d_ws;
  size_t off = 0;
  ushort* Ab     = (ushort*)(ws + off); off = align256(off + (size_t)NN*256*2);  // reused as h1b
  ushort* featb  = (ushort*)(ws + off); off = align256(off + (size_t)NN*256*2);
  ushort* feat2  = (ushort*)(ws + off); off = align256(off + (size_t)NN*128*2);  // f16
  float* el1     = (float*)(ws + off);  off = align256(off + (size_t)NN*4*4);
  float* er1     = (float*)(ws + off);  off = align256(off + (size_t)NN*4*4);
  int* rowptr    = (int*)(ws + off);    off = align256(off + (size_t)(NN+1)*4);
  int* cnt       = (int*)(ws + off);    off = align256(off + (size_t)NN*4);
  int* cursor    = (int*)(ws + off);    off = align256(off + (size_t)NN*4);
  int* csr_src   = (int*)(ws + off);    off = align256(off + (size_t)EE*4);
  ushort* Bth1   = (ushort*)(ws + off); off = align256(off + (size_t)256*256*2);
  ushort* Btl1   = (ushort*)(ws + off); off = align256(off + (size_t)256*256*2);
  ushort* Bth2   = (ushort*)(ws + off); off = align256(off + (size_t)128*256*2);
  ushort* Btl2   = (ushort*)(ws + off); off = align256(off + (size_t)128*256*2);
  int* bsum      = (int*)(ws + off);    off = align256(off + (size_t)64*4);
  if (off > ws_size) return;  // fail loudly: output stays poisoned

  ushort* h1b = Ab;
  float* el2 = el1;
  float* er2 = er1;

  const int EB = (EE + 255)/256;
  const int FB = (NN + 3)/4;
  const int MT = (NN + 127)/128;

  // memset + merged prep/hist, then CSR chain (boff merged into scan_write)
  hipMemsetAsync(cnt, 0, (size_t)NN*4, stream);
  k_prep<<<6762 + (EE/256), 256, 0, stream>>>(h_in, Ab, W1, Bth1, Btl1, W2, Bth2, Btl2, dst, cnt);
  k_scan_bsum<<<NB_SCAN, 1024, 0, stream>>>(cnt, bsum, NN);
  k_scan_write<<<NB_SCAN, 1024, 0, stream>>>(cnt, bsum, rowptr, cursor, NN);
  k_scatter<<<EB, 256, 0, stream>>>(src, dst, cursor, csr_src, EE);

  // ----- layer 1 -----
  k_mgemm<1><<<dim3(2, MT), 512, 0, stream>>>(Ab, Bth1, Btl1, featb, al1, ar1, el1, er1, NN, 256, 256);
  k_fused1<<<FB, 256, 0, stream>>>(rowptr, csr_src, el1, er1, featb, h1b);

  // ----- layer 2 -----
  k_mgemm<2><<<dim3(1, MT), 512, 0, stream>>>(h1b, Bth2, Btl2, feat2, al2, ar2, el2, er2, NN, 256, 128);
  k_fused2<<<FB, 256, 0, stream>>>(rowptr, csr_src, el2, er2, feat2, out);
}